// Round 7
// baseline (588.121 us; speedup 1.0000x reference)
//
#include <hip/hip_runtime.h>
#include <stdint.h>

// VectorQuantizer — bit-exact replication of the fp32 numpy reference.
//   d = sum(z*z,1)[:,None] + sum(c*c,1)[None,:] - 2.0*einsum('nc,kc->nk',z,c)
// sums: numpy pairwise_sum n=64 (8 accumulators + fixed tree). einsum: AVX512
// order — 16 chained-FMA lanes over 4 blocks of 16, then reduce_add tree.
//
// Round 7 theory: busy ~90us is invariant across 7 variants; the stall
// (~48us best) is the row-fetch mechanism. s_load returns are OUT-OF-ORDER
// -> only lgkmcnt(0) full-drain waits -> un-pipelineable (r5, 137us, 65%
// VALU duty). LDS staging pipelines but 135KB -> 1 block/CU -> 2 waves/SIMD
// killed TLP, plus the epilogue gather was a 32-way bank conflict (r6, 7.8M
// conflicts, 200us). Fix: VECTOR global_load of the row. VMEM returns are
// IN-ORDER -> compiler emits counted vmcnt(N) and software-pipelines chunk
// loads under FMAs, with zero LDS cost (occupancy stays ~4 waves/SIMD).
// All lanes load the same address -> TA broadcast; codebook is L1/L2
// resident. Vector path forced by laundering the row pointer through an
// empty asm ("+v") so uniformity can't be proven (else clang picks s_load).
// Row consumed in 4 chunks of 16ch in the chain's natural order 48->32->16->0
// (innermost-first nesting: identical value sequence, bit-exact), two
// alternating 16-float buffers so next chunk's loads overlap current FMAs.
//
// Structure (= r5, 137us baseline): 1 point/lane, 4-wave k-split (wave g:
// k in [128g,128g+128)), block = 64 points, 2048 blocks. cnorm precomputed
// once into d_ws, broadcast-read from LDS. Argmin over ascending disjoint
// k-ranges combined with strict < (first occurrence).

#pragma clang fp contract(off)

#define KCODES 512
#define CDIM 64
#define HW 4096              // 64*64
#define ZQ_ELEMS 8388608     // 32*64*64*64

// np.sum(row*row): pairwise_sum n=64 replica (products pre-rounded), one row
static __device__ __forceinline__ float cnorm_row(const float* __restrict__ row) {
    float r[8];
    #pragma unroll
    for (int j = 0; j < 8; ++j) r[j] = row[j] * row[j];
    #pragma unroll
    for (int i = 8; i < 64; i += 8) {
        #pragma unroll
        for (int j = 0; j < 8; ++j) r[j] = r[j] + row[i + j] * row[i + j];
    }
    return ((r[0] + r[1]) + (r[2] + r[3])) + ((r[4] + r[5]) + (r[6] + r[7]));
}

// One-shot: cnorm[512] into workspace. 2 blocks x 256 threads.
__global__ void cnorm_kernel(const float* __restrict__ cb,
                             float* __restrict__ cnorm_out) {
    int k = (int)blockIdx.x * 256 + (int)threadIdx.x;
    if (k < KCODES) cnorm_out[k] = cnorm_row(cb + (size_t)k * CDIM);
}

__global__ __launch_bounds__(256)
void vq_kernel(
    const float* __restrict__ z_e,
    const float* __restrict__ cb,
    const float* __restrict__ cnorm_g,   // precomputed (d_ws) or nullptr
    float* __restrict__ out)
{
    __shared__ float cnorm[KCODES];
    __shared__ float dcand[4 * 64];
    __shared__ int   kcand[4 * 64];

    if (cnorm_g) {
        // coalesced 2KB load: 2 x 4B/lane, stride-1
        #pragma unroll
        for (int k = (int)threadIdx.x; k < KCODES; k += 256)
            cnorm[k] = cnorm_g[k];
    } else {
        // fallback (ws too small): in-block compute, bit-identical
        for (int k = (int)threadIdx.x; k < KCODES; k += 256)
            cnorm[k] = cnorm_row(cb + (size_t)k * CDIM);
    }

    // block = 64 consecutive points; wave g covers k in [128g, 128g+128)
    const int lane = (int)threadIdx.x & 63;
    const int g = __builtin_amdgcn_readfirstlane((int)threadIdx.x >> 6);
    const int n0 = (int)blockIdx.x * 64;
    const int b = n0 / HW;
    const int hw0 = n0 % HW;
    const float* zp = z_e + (size_t)b * CDIM * HW + hw0 + lane;

    // one point per lane: zz[m] = z[channel m]; 64 coalesced 256B loads
    float zz[CDIM];
    #pragma unroll
    for (int m = 0; m < CDIM; ++m)
        zz[m] = zp[(size_t)m * HW];

    // np.sum(z*z, axis=1): pairwise replica (products pre-rounded)
    float sz;
    {
        float r[8];
        #pragma unroll
        for (int j = 0; j < 8; ++j) r[j] = zz[j] * zz[j];
        #pragma unroll
        for (int i = 8; i < 64; i += 8) {
            #pragma unroll
            for (int j = 0; j < 8; ++j) r[j] = r[j] + zz[i + j] * zz[i + j];
        }
        sz = ((r[0] + r[1]) + (r[2] + r[3])) + ((r[4] + r[5]) + (r[6] + r[7]));
    }

    __syncthreads();

    float best = 3.4e38f;
    int bk = 0;
    const int k0 = g * 128;

    // row pointer for this wave's k-slice, laundered into VGPRs so the
    // compiler cannot prove uniformity -> global_load (in-order vmcnt)
    // instead of s_load (out-of-order lgkm, un-pipelineable).
    uintptr_t cpu_ = (uintptr_t)(cb + (size_t)k0 * CDIM);
    asm("" : "+v"(cpu_));
    const float4* cp = (const float4*)cpu_;   // 16 float4 per row

    for (int i = 0; i < 128; ++i) {
        const int k = k0 + i;

        // chunk loads in consumption order (chains nest innermost-first:
        // channels 48-63, then 32-47, 16-31, 0-15); two alternating
        // buffers A,B so the next chunk's loads overlap current FMAs.
        float4 A0 = cp[12], A1 = cp[13], A2 = cp[14], A3 = cp[15]; // ch 48-63
        float4 B0 = cp[8],  B1 = cp[9],  B2 = cp[10], B3 = cp[11]; // ch 32-47

        float v[16];
        // stage 3: v[l] = fma(z[48+l], c[48+l], 0)
        {
            const float* ca = (const float*)&A0;  // A0..A3 contiguous? no —
            (void)ca;
        }
        // component access via compile-time switch (l/4 selects buffer reg)
        #define QC(Q0,Q1,Q2,Q3,l) \
            ((l) < 4 ? ((l)==0?Q0.x:(l)==1?Q0.y:(l)==2?Q0.z:Q0.w) : \
             (l) < 8 ? ((l)==4?Q1.x:(l)==5?Q1.y:(l)==6?Q1.z:Q1.w) : \
             (l) <12 ? ((l)==8?Q2.x:(l)==9?Q2.y:(l)==10?Q2.z:Q2.w) : \
                       ((l)==12?Q3.x:(l)==13?Q3.y:(l)==14?Q3.z:Q3.w))

        #pragma unroll
        for (int l = 0; l < 16; ++l)
            v[l] = fmaf(zz[48 + l], QC(A0,A1,A2,A3,l), 0.f);

        A0 = cp[4]; A1 = cp[5]; A2 = cp[6]; A3 = cp[7];            // ch 16-31

        #pragma unroll
        for (int l = 0; l < 16; ++l)
            v[l] = fmaf(zz[32 + l], QC(B0,B1,B2,B3,l), v[l]);

        B0 = cp[0]; B1 = cp[1]; B2 = cp[2]; B3 = cp[3];            // ch 0-15

        #pragma unroll
        for (int l = 0; l < 16; ++l)
            v[l] = fmaf(zz[16 + l], QC(A0,A1,A2,A3,l), v[l]);

        #pragma unroll
        for (int l = 0; l < 16; ++l)
            v[l] = fmaf(zz[l], QC(B0,B1,B2,B3,l), v[l]);
        #undef QC

        // reduce_add tree: e[l]=v[l]+v[8+l]; f[l]=e[l]+e[4+l];
        // dot = (f0+f2) + (f1+f3)
        float e[8];
        #pragma unroll
        for (int l = 0; l < 8; ++l) e[l] = v[l] + v[8 + l];
        float f[4];
        #pragma unroll
        for (int l = 0; l < 4; ++l) f[l] = e[l] + e[4 + l];
        float g0 = f[0] + f[2];
        float g1 = f[1] + f[3];
        float dot = g0 + g1;

        float Aa = sz + cnorm[k];              // fl(sz + sc_k)
        float d = fmaf(dot, -2.f, Aa);         // == fl(A - 2*dot): 2*dot exact

        if (d < best) { best = d; bk = k; }    // strict <: first occurrence

        cp += 16;                              // next row (256B)
    }

    dcand[g * 64 + lane] = best;
    kcand[g * 64 + lane] = bk;
    __syncthreads();

    // combine over ascending k-ranges (strict < keeps first occurrence)
    float bd = dcand[lane];
    int bi = kcand[lane];
    #pragma unroll
    for (int gg = 1; gg < 4; ++gg) {
        float d2 = dcand[gg * 64 + lane];
        int   k2 = kcand[gg * 64 + lane];
        if (d2 < bd) { bd = d2; bi = k2; }
    }

    // indices (as float32, second output region) — wave 0 only
    if (g == 0) out[ZQ_ELEMS + n0 + lane] = (float)bi;

    // z_q: wave g writes channels [16g, 16g+16); coalesced 4B/lane stores
    const float* row = cb + (size_t)bi * CDIM;
    float* op = out + (size_t)b * CDIM * HW + hw0 + lane;
    #pragma unroll
    for (int c = 0; c < 16; ++c) {
        const int ch = g * 16 + c;
        op[(size_t)ch * HW] = row[ch];
    }
}

extern "C" void kernel_launch(void* const* d_in, const int* in_sizes, int n_in,
                              void* d_out, int out_size, void* d_ws, size_t ws_size,
                              hipStream_t stream) {
    const float* z_e = (const float*)d_in[0];
    const float* cb  = (const float*)d_in[1];
    float* out = (float*)d_out;

    float* cnorm_ws = nullptr;
    if (ws_size >= KCODES * sizeof(float)) {
        cnorm_ws = (float*)d_ws;
        cnorm_kernel<<<dim3(2), dim3(256), 0, stream>>>(cb, cnorm_ws);
    }
    vq_kernel<<<dim3(2048), dim3(256), 0, stream>>>(z_e, cb, cnorm_ws, out);
}

// Round 8
// 225.964 us; speedup vs baseline: 2.6027x; 2.6027x over previous
//
#include <hip/hip_runtime.h>
#include <stdint.h>

// VectorQuantizer — bit-exact replication of the fp32 numpy reference.
//   d = sum(z*z,1)[:,None] + sum(c*c,1)[None,:] - 2.0*einsum('nc,kc->nk',z,c)
// sums: numpy pairwise_sum n=64 (8 accumulators + fixed tree). einsum: AVX512
// order — 16 chained-FMA lanes over 4 blocks of 16, then reduce_add tree.
//
// Round 8: fetch mechanisms fully characterized by r5/r6/r7:
//   s_load  (r5, 137us): sL1 fill serialization ~90cy/iter exposed; TLP-
//           immune (drafting waves stall on the SAME line).
//   vector global (r7, 575us): TA processes all 64 lane addresses even when
//           identical (~41cy/load measured) — dead.
//   LDS uniform ds_read (r6, 201us): busy 94us @46% duty — NOT LDS-pipe-
//           bound (that predicts 35% duty); it was 2 waves/SIMD latency
//           exposure + 32-way-conflict LDS epilogue gather + r[64] register
//           blowup.
// This round = r6 with all three defects fixed:
//   (a) 1024-thread blocks: 16 waves/CU = 4 waves/SIMD at the same
//       1-block/CU LDS footprint (LDS cost per-block, waves per-block —
//       doubling block size doubles TLP for free).
//   (b) row consumed float4-wise via two rotating 4xfloat4 buffers
//       (~120 live regs, fits the hard 128-reg/wave bound that
//       __launch_bounds__(1024) enforces; no r[64] materialization).
//   (c) epilogue gathers winning rows from GLOBAL cb (L2-hot), not LDS —
//       zero bank conflicts.
// Inner loop: 16 uniform ds_read_b128 (in-order, counted lgkmcnt ->
// compiler software-pipelines across unroll-2 iterations) + the proven
// bit-exact chain (stages ch48->32->16->0, innermost-first).
//
// Structure: 1 point/lane, 16 waves = 4 point-groups x 4-way k-split,
// 256 points/block, 512 blocks, 8192 waves (same as r5). Argmin over
// ascending disjoint k-ranges combined with strict < (first occurrence).

#pragma clang fp contract(off)

#define KCODES 512
#define CDIM 64
#define HW 4096              // 64*64
#define ZQ_ELEMS 8388608     // 32*64*64*64
#define NPB 256              // points per block

// dynamic LDS layout (float index):
//   [0, 32768)        codebook 512x64
//   [32768, 33280)    cnorm[512]
//   [33280, 34304)    dcand [4 rng][256]
//   [34304, 35328)    kcand [4 rng][256]  (int)
//   [35328, 35584)    kbest [256]         (int)
#define LDS_FLOATS 35584
#define LDS_BYTES  (LDS_FLOATS * 4)

// np.sum(row*row): pairwise_sum n=64 replica (products pre-rounded), one row
static __device__ __forceinline__ float cnorm_row(const float* __restrict__ row) {
    float r[8];
    #pragma unroll
    for (int j = 0; j < 8; ++j) r[j] = row[j] * row[j];
    #pragma unroll
    for (int i = 8; i < 64; i += 8) {
        #pragma unroll
        for (int j = 0; j < 8; ++j) r[j] = r[j] + row[i + j] * row[i + j];
    }
    return ((r[0] + r[1]) + (r[2] + r[3])) + ((r[4] + r[5]) + (r[6] + r[7]));
}

// One-shot: cnorm[512] into workspace. 2 blocks x 256 threads.
__global__ void cnorm_kernel(const float* __restrict__ cb,
                             float* __restrict__ cnorm_out) {
    int k = (int)blockIdx.x * 256 + (int)threadIdx.x;
    if (k < KCODES) cnorm_out[k] = cnorm_row(cb + (size_t)k * CDIM);
}

// component access: compile-time switch, Q(l/4) register, component l%4
#define QC(Q0,Q1,Q2,Q3,l) \
    ((l) < 4 ? ((l)==0?Q0.x:(l)==1?Q0.y:(l)==2?Q0.z:Q0.w) : \
     (l) < 8 ? ((l)==4?Q1.x:(l)==5?Q1.y:(l)==6?Q1.z:Q1.w) : \
     (l) <12 ? ((l)==8?Q2.x:(l)==9?Q2.y:(l)==10?Q2.z:Q2.w) : \
               ((l)==12?Q3.x:(l)==13?Q3.y:(l)==14?Q3.z:Q3.w))

// ---------------- LDS-codebook kernel (primary path) ----------------
__global__ __launch_bounds__(1024)
void vq_lds(const float* __restrict__ z_e,
            const float* __restrict__ cb,
            const float* __restrict__ cnorm_g,   // precomputed (d_ws) or nullptr
            float* __restrict__ out)
{
    extern __shared__ float smem[];
    float* cbs   = smem;                    // 32768 floats
    float* cnorm = smem + 32768;            // 512
    float* dcand = smem + 33280;            // 1024 = [4][256]
    int*   kcand = (int*)(smem + 34304);    // 1024
    int*   kbest = (int*)(smem + 35328);    // 256

    const int tid = (int)threadIdx.x;

    // stage codebook: 1024 threads x 8 float4 = 128KB, coalesced, bitwise
    {
        const float4* src = (const float4*)cb;
        float4* dst = (float4*)cbs;
        #pragma unroll
        for (int j = 0; j < 8; ++j)
            dst[tid + 1024 * j] = src[tid + 1024 * j];
    }
    if (tid < KCODES)
        cnorm[tid] = cnorm_g ? cnorm_g[tid] : cnorm_row(cb + (size_t)tid * CDIM);

    // wave decomposition: 16 waves = 4 point-groups x 4 k-ranges
    const int lane = tid & 63;
    const int wid  = __builtin_amdgcn_readfirstlane(tid >> 6);
    const int g    = wid & 3;        // k-range
    const int pgrp = wid >> 2;       // point group (64 points each)

    const int n0 = (int)blockIdx.x * NPB;      // 256 | HW -> single image
    const int b = n0 / HW;
    const int hw0 = n0 % HW;
    const float* zp = z_e + (size_t)b * CDIM * HW + hw0 + pgrp * 64 + lane;

    // one point per lane: zz[m] = z[channel m]; coalesced 256B loads
    float zz[CDIM];
    #pragma unroll
    for (int m = 0; m < CDIM; ++m)
        zz[m] = zp[(size_t)m * HW];

    // np.sum(z*z, axis=1): pairwise replica (products pre-rounded)
    float sz;
    {
        float r[8];
        #pragma unroll
        for (int j = 0; j < 8; ++j) r[j] = zz[j] * zz[j];
        #pragma unroll
        for (int i = 8; i < 64; i += 8) {
            #pragma unroll
            for (int j = 0; j < 8; ++j) r[j] = r[j] + zz[i + j] * zz[i + j];
        }
        sz = ((r[0] + r[1]) + (r[2] + r[3])) + ((r[4] + r[5]) + (r[6] + r[7]));
    }

    __syncthreads();   // codebook + cnorm staged

    float best = 3.4e38f;
    int bk = 0;
    const int k0 = g * 128;

    #pragma unroll 2
    for (int i = 0; i < 128; ++i) {
        const int k = k0 + i;
        const float4* ck4 = (const float4*)(cbs + (size_t)k * CDIM);
        const float An = sz + cnorm[k];        // fl(sz + sc_k), uniform b32

        // rotating 4xfloat4 buffers; reads in consumption order
        // (chains nest innermost-first: ch 48-63, 32-47, 16-31, 0-15)
        float4 a0 = ck4[12], a1 = ck4[13], a2 = ck4[14], a3 = ck4[15];
        float4 b0 = ck4[8],  b1 = ck4[9],  b2 = ck4[10], b3 = ck4[11];

        float v[16];
        #pragma unroll
        for (int l = 0; l < 16; ++l)
            v[l] = fmaf(zz[48 + l], QC(a0,a1,a2,a3,l), 0.f);

        a0 = ck4[4]; a1 = ck4[5]; a2 = ck4[6]; a3 = ck4[7];

        #pragma unroll
        for (int l = 0; l < 16; ++l)
            v[l] = fmaf(zz[32 + l], QC(b0,b1,b2,b3,l), v[l]);

        b0 = ck4[0]; b1 = ck4[1]; b2 = ck4[2]; b3 = ck4[3];

        #pragma unroll
        for (int l = 0; l < 16; ++l)
            v[l] = fmaf(zz[16 + l], QC(a0,a1,a2,a3,l), v[l]);

        #pragma unroll
        for (int l = 0; l < 16; ++l)
            v[l] = fmaf(zz[l], QC(b0,b1,b2,b3,l), v[l]);

        // reduce_add tree: e[l]=v[l]+v[8+l]; f[l]=e[l]+e[4+l];
        // dot = (f0+f2) + (f1+f3)
        float e[8];
        #pragma unroll
        for (int l = 0; l < 8; ++l) e[l] = v[l] + v[8 + l];
        float f[4];
        #pragma unroll
        for (int l = 0; l < 4; ++l) f[l] = e[l] + e[4 + l];
        float g0 = f[0] + f[2];
        float g1 = f[1] + f[3];
        float dot = g0 + g1;

        float d = fmaf(dot, -2.f, An);         // == fl(A - 2*dot): 2*dot exact

        if (d < best) { best = d; bk = k; }    // strict <: first occurrence
    }

    dcand[g * NPB + pgrp * 64 + lane] = best;
    kcand[g * NPB + pgrp * 64 + lane] = bk;
    __syncthreads();

    // combine over ascending k-ranges (strict < keeps first occurrence)
    if (tid < NPB) {
        float bd = dcand[tid];
        int bi = kcand[tid];
        #pragma unroll
        for (int gg = 1; gg < 4; ++gg) {
            float d2 = dcand[gg * NPB + tid];
            int   k2 = kcand[gg * NPB + tid];
            if (d2 < bd) { bd = d2; bi = k2; }
        }
        out[ZQ_ELEMS + n0 + tid] = (float)bi;  // indices (as float32)
        kbest[tid] = bi;
    }
    __syncthreads();

    // z_q: wave (pgrp,g) writes channels [16g,16g+16) for its 64 points;
    // gather from GLOBAL cb (L2-hot) — avoids the r6 LDS 32-way conflict
    const int bi = kbest[pgrp * 64 + lane];
    const float* row = cb + (size_t)bi * CDIM;
    float* op = out + (size_t)b * CDIM * HW + hw0 + pgrp * 64 + lane;
    #pragma unroll
    for (int c = 0; c < 16; ++c) {
        const int ch = g * 16 + c;
        op[(size_t)ch * HW] = row[ch];
    }
}

// ---------------- s_load fallback (proven r5 kernel, 137us) ----------------
__global__ __launch_bounds__(256)
void vq_sload(const float* __restrict__ z_e,
              const float* __restrict__ cb,
              const float* __restrict__ cnorm_g,
              float* __restrict__ out)
{
    __shared__ float cnorm[KCODES];
    __shared__ float dcand[4 * 64];
    __shared__ int   kcand[4 * 64];

    if (cnorm_g) {
        #pragma unroll
        for (int k = (int)threadIdx.x; k < KCODES; k += 256)
            cnorm[k] = cnorm_g[k];
    } else {
        for (int k = (int)threadIdx.x; k < KCODES; k += 256)
            cnorm[k] = cnorm_row(cb + (size_t)k * CDIM);
    }

    const int lane = (int)threadIdx.x & 63;
    const int g = __builtin_amdgcn_readfirstlane((int)threadIdx.x >> 6);
    const int n0 = (int)blockIdx.x * 64;
    const int b = n0 / HW;
    const int hw0 = n0 % HW;
    const float* zp = z_e + (size_t)b * CDIM * HW + hw0 + lane;

    float zz[CDIM];
    #pragma unroll
    for (int m = 0; m < CDIM; ++m)
        zz[m] = zp[(size_t)m * HW];

    float sz;
    {
        float r[8];
        #pragma unroll
        for (int j = 0; j < 8; ++j) r[j] = zz[j] * zz[j];
        #pragma unroll
        for (int i = 8; i < 64; i += 8) {
            #pragma unroll
            for (int j = 0; j < 8; ++j) r[j] = r[j] + zz[i + j] * zz[i + j];
        }
        sz = ((r[0] + r[1]) + (r[2] + r[3])) + ((r[4] + r[5]) + (r[6] + r[7]));
    }

    __syncthreads();

    float best = 3.4e38f;
    int bk = 0;
    const int k0 = g * 128;

    for (int i = 0; i < 128; ++i) {
        const int k = k0 + i;
        const float* ck = cb + (size_t)k * CDIM;

        float v[16];
        #pragma unroll
        for (int l = 0; l < 16; ++l)
            v[l] = fmaf(zz[l], ck[l],
                     fmaf(zz[16 + l], ck[16 + l],
                       fmaf(zz[32 + l], ck[32 + l],
                         fmaf(zz[48 + l], ck[48 + l], 0.f))));

        float e[8];
        #pragma unroll
        for (int l = 0; l < 8; ++l) e[l] = v[l] + v[8 + l];
        float f[4];
        #pragma unroll
        for (int l = 0; l < 4; ++l) f[l] = e[l] + e[4 + l];
        float g0 = f[0] + f[2];
        float g1 = f[1] + f[3];
        float dot = g0 + g1;

        float A = sz + cnorm[k];
        float d = fmaf(dot, -2.f, A);

        if (d < best) { best = d; bk = k; }
    }

    dcand[g * 64 + lane] = best;
    kcand[g * 64 + lane] = bk;
    __syncthreads();

    float bd = dcand[lane];
    int bi = kcand[lane];
    #pragma unroll
    for (int gg = 1; gg < 4; ++gg) {
        float d2 = dcand[gg * 64 + lane];
        int   k2 = kcand[gg * 64 + lane];
        if (d2 < bd) { bd = d2; bi = k2; }
    }

    if (g == 0) out[ZQ_ELEMS + n0 + lane] = (float)bi;

    const float* row = cb + (size_t)bi * CDIM;
    float* op = out + (size_t)b * CDIM * HW + hw0 + lane;
    #pragma unroll
    for (int c = 0; c < 16; ++c) {
        const int ch = g * 16 + c;
        op[(size_t)ch * HW] = row[ch];
    }
}

extern "C" void kernel_launch(void* const* d_in, const int* in_sizes, int n_in,
                              void* d_out, int out_size, void* d_ws, size_t ws_size,
                              hipStream_t stream) {
    const float* z_e = (const float*)d_in[0];
    const float* cb  = (const float*)d_in[1];
    float* out = (float*)d_out;

    float* cnorm_ws = nullptr;
    if (ws_size >= KCODES * sizeof(float)) {
        cnorm_ws = (float*)d_ws;
        cnorm_kernel<<<dim3(2), dim3(256), 0, stream>>>(cb, cnorm_ws);
    }

    // opt in to >64KB dynamic LDS (gfx950: up to 160KB/workgroup);
    // host-side metadata call, not a stream op (graph-capture safe)
    static int lds_ok = -1;
    if (lds_ok < 0) {
        lds_ok = (hipFuncSetAttribute((const void*)vq_lds,
                                      hipFuncAttributeMaxDynamicSharedMemorySize,
                                      LDS_BYTES) == hipSuccess) ? 1 : 0;
    }

    if (lds_ok == 1) {
        vq_lds<<<dim3(131072 / NPB), dim3(1024), LDS_BYTES, stream>>>(
            z_e, cb, cnorm_ws, out);
    } else {
        vq_sload<<<dim3(2048), dim3(256), 0, stream>>>(z_e, cb, cnorm_ws, out);
    }
}

// Round 9
// 212.742 us; speedup vs baseline: 2.7645x; 1.0622x over previous
//
#include <hip/hip_runtime.h>
#include <stdint.h>

// VectorQuantizer — bit-exact replication of the fp32 numpy reference.
//   d = sum(z*z,1)[:,None] + sum(c*c,1)[None,:] - 2.0*einsum('nc,kc->nk',z,c)
// sums: numpy pairwise_sum n=64 (8 accumulators + fixed tree). einsum: AVX512
// order — 16 chained-FMA lanes over 4 blocks of 16, then reduce_add tree.
//
// Round 9 theory: r8 (LDS codebook, 1024-thr, 4 waves/SIMD) = 177us, busy
// 94us, conflicts 0 — remaining stall is LDS-PIPE OCCUPANCY, not latency:
// 16 waves/CU x 16 ds_read_b128/iter (~8cy each) = ~2048cy demand on the
// single per-CU LDS pipe vs 672cy VALU demand per SIMD. Broadcast reads are
// conflict-free but still occupy the pipe per instruction. Fix: HALVE LDS
// traffic per (n,k) pair -> 2 points/lane. Config that fits registers:
// 512-thread blocks (8 waves -> 256-VGPR cap; ~220 live), 8 waves = 4 krng
// x 2 pgrp, 256 pts/block, 512 blocks. Per iter: 16 LDS reads feed 128
// pairs (336cy VALU) -> per-CU LDS ~1024cy vs VALU 672cy, near balance;
// ds latency (in-order, counted lgkm) hides under the compute stream.
// Row read once per k, feeds both points' chains (A/B interleaved at the
// instruction level only — each point's scalar sequence is untouched).
//
// Structure: 2 points/lane, 4-wave-pair k-split (range g: k in
// [128g,128g+128)), 256 points/block, 512 blocks. Codebook + cnorm staged
// to LDS once (139KB, 1 block/CU). Epilogue gathers winning rows from
// GLOBAL cb (L2-hot; zero LDS bank conflicts, proven r8). Argmin over
// ascending disjoint k-ranges combined with strict < (first occurrence).

#pragma clang fp contract(off)

#define KCODES 512
#define CDIM 64
#define HW 4096              // 64*64
#define ZQ_ELEMS 8388608     // 32*64*64*64
#define NPB 256              // points per block

// dynamic LDS layout (float index):
//   [0, 32768)        codebook 512x64
//   [32768, 33280)    cnorm[512]
//   [33280, 34304)    dcand [4 rng][256]
//   [34304, 35328)    kcand [4 rng][256]  (int)
//   [35328, 35584)    kbest [256]         (int)
#define LDS_FLOATS 35584
#define LDS_BYTES  (LDS_FLOATS * 4)

// np.sum(row*row): pairwise_sum n=64 replica (products pre-rounded), one row
static __device__ __forceinline__ float cnorm_row(const float* __restrict__ row) {
    float r[8];
    #pragma unroll
    for (int j = 0; j < 8; ++j) r[j] = row[j] * row[j];
    #pragma unroll
    for (int i = 8; i < 64; i += 8) {
        #pragma unroll
        for (int j = 0; j < 8; ++j) r[j] = r[j] + row[i + j] * row[i + j];
    }
    return ((r[0] + r[1]) + (r[2] + r[3])) + ((r[4] + r[5]) + (r[6] + r[7]));
}

// One-shot: cnorm[512] into workspace. 2 blocks x 256 threads.
__global__ void cnorm_kernel(const float* __restrict__ cb,
                             float* __restrict__ cnorm_out) {
    int k = (int)blockIdx.x * 256 + (int)threadIdx.x;
    if (k < KCODES) cnorm_out[k] = cnorm_row(cb + (size_t)k * CDIM);
}

// np.sum(z*z, axis=1): pairwise replica (products pre-rounded)
static __device__ __forceinline__ float znorm_pairwise(const float* zz) {
    float r[8];
    #pragma unroll
    for (int j = 0; j < 8; ++j) r[j] = zz[j] * zz[j];
    #pragma unroll
    for (int i = 8; i < 64; i += 8) {
        #pragma unroll
        for (int j = 0; j < 8; ++j) r[j] = r[j] + zz[i + j] * zz[i + j];
    }
    return ((r[0] + r[1]) + (r[2] + r[3])) + ((r[4] + r[5]) + (r[6] + r[7]));
}

// component access: compile-time switch, Q(l/4) register, component l%4
#define QC(Q0,Q1,Q2,Q3,l) \
    ((l) < 4 ? ((l)==0?Q0.x:(l)==1?Q0.y:(l)==2?Q0.z:Q0.w) : \
     (l) < 8 ? ((l)==4?Q1.x:(l)==5?Q1.y:(l)==6?Q1.z:Q1.w) : \
     (l) <12 ? ((l)==8?Q2.x:(l)==9?Q2.y:(l)==10?Q2.z:Q2.w) : \
               ((l)==12?Q3.x:(l)==13?Q3.y:(l)==14?Q3.z:Q3.w))

// ---------------- LDS-codebook kernel, 2 pts/lane (primary) ----------------
__global__ __launch_bounds__(512)
void vq_lds(const float* __restrict__ z_e,
            const float* __restrict__ cb,
            const float* __restrict__ cnorm_g,   // precomputed (d_ws) or nullptr
            float* __restrict__ out)
{
    extern __shared__ float smem[];
    float* cbs   = smem;                    // 32768 floats
    float* cnorm = smem + 32768;            // 512
    float* dcand = smem + 33280;            // 1024 = [4][256]
    int*   kcand = (int*)(smem + 34304);    // 1024
    int*   kbest = (int*)(smem + 35328);    // 256

    const int tid = (int)threadIdx.x;

    // stage codebook: 512 threads x 16 float4 = 128KB, coalesced, bitwise
    {
        const float4* src = (const float4*)cb;
        float4* dst = (float4*)cbs;
        #pragma unroll
        for (int j = 0; j < 16; ++j)
            dst[tid + 512 * j] = src[tid + 512 * j];
    }
    if (tid < KCODES)
        cnorm[tid] = cnorm_g ? cnorm_g[tid] : cnorm_row(cb + (size_t)tid * CDIM);

    // wave decomposition: 8 waves = 2 point-groups x 4 k-ranges
    const int lane = tid & 63;
    const int wid  = __builtin_amdgcn_readfirstlane(tid >> 6);
    const int g    = wid & 3;        // k-range
    const int pgrp = wid >> 2;       // point group (128 points each)

    const int n0 = (int)blockIdx.x * NPB;      // 256 | HW -> single image
    const int b = n0 / HW;
    const int hw0 = n0 % HW;
    const float* zpa = z_e + (size_t)b * CDIM * HW + hw0 + pgrp * 128 + lane;
    const float* zpb = zpa + 64;

    // two points per lane: zz[m] = z[channel m]; coalesced 256B loads
    float zza[CDIM], zzb[CDIM];
    #pragma unroll
    for (int m = 0; m < CDIM; ++m) zza[m] = zpa[(size_t)m * HW];
    #pragma unroll
    for (int m = 0; m < CDIM; ++m) zzb[m] = zpb[(size_t)m * HW];

    const float sza = znorm_pairwise(zza);
    const float szb = znorm_pairwise(zzb);

    __syncthreads();   // codebook + cnorm staged

    float best_a = 3.4e38f, best_b = 3.4e38f;
    int bk_a = 0, bk_b = 0;
    const int k0 = g * 128;

    for (int i = 0; i < 128; ++i) {
        const int k = k0 + i;
        const float4* ck4 = (const float4*)(cbs + (size_t)k * CDIM);
        const float cnk = cnorm[k];            // one uniform b32, shared A/B
        const float Ana = sza + cnk;           // fl(sz + sc_k)
        const float Anb = szb + cnk;

        // rotating 4xfloat4 buffers; reads in consumption order
        // (chains nest innermost-first: ch 48-63, 32-47, 16-31, 0-15);
        // each row read ONCE, feeds both points' chains.
        float4 q0 = ck4[12], q1 = ck4[13], q2 = ck4[14], q3 = ck4[15];
        float4 r0 = ck4[8],  r1 = ck4[9],  r2 = ck4[10], r3 = ck4[11];

        float va[16], vb[16];
        #pragma unroll
        for (int l = 0; l < 16; ++l) {
            const float c = QC(q0,q1,q2,q3,l);
            va[l] = fmaf(zza[48 + l], c, 0.f);
            vb[l] = fmaf(zzb[48 + l], c, 0.f);
        }

        q0 = ck4[4]; q1 = ck4[5]; q2 = ck4[6]; q3 = ck4[7];

        #pragma unroll
        for (int l = 0; l < 16; ++l) {
            const float c = QC(r0,r1,r2,r3,l);
            va[l] = fmaf(zza[32 + l], c, va[l]);
            vb[l] = fmaf(zzb[32 + l], c, vb[l]);
        }

        r0 = ck4[0]; r1 = ck4[1]; r2 = ck4[2]; r3 = ck4[3];

        #pragma unroll
        for (int l = 0; l < 16; ++l) {
            const float c = QC(q0,q1,q2,q3,l);
            va[l] = fmaf(zza[16 + l], c, va[l]);
            vb[l] = fmaf(zzb[16 + l], c, vb[l]);
        }

        #pragma unroll
        for (int l = 0; l < 16; ++l) {
            const float c = QC(r0,r1,r2,r3,l);
            va[l] = fmaf(zza[l], c, va[l]);
            vb[l] = fmaf(zzb[l], c, vb[l]);
        }

        // reduce_add tree per point: e[l]=v[l]+v[8+l]; f[l]=e[l]+e[4+l];
        // dot = (f0+f2) + (f1+f3)
        {
            float e[8];
            #pragma unroll
            for (int l = 0; l < 8; ++l) e[l] = va[l] + va[8 + l];
            float f[4];
            #pragma unroll
            for (int l = 0; l < 4; ++l) f[l] = e[l] + e[4 + l];
            float g0 = f[0] + f[2];
            float g1 = f[1] + f[3];
            float dot = g0 + g1;
            float d = fmaf(dot, -2.f, Ana);    // == fl(A - 2*dot): 2*dot exact
            if (d < best_a) { best_a = d; bk_a = k; }   // strict <
        }
        {
            float e[8];
            #pragma unroll
            for (int l = 0; l < 8; ++l) e[l] = vb[l] + vb[8 + l];
            float f[4];
            #pragma unroll
            for (int l = 0; l < 4; ++l) f[l] = e[l] + e[4 + l];
            float g0 = f[0] + f[2];
            float g1 = f[1] + f[3];
            float dot = g0 + g1;
            float d = fmaf(dot, -2.f, Anb);
            if (d < best_b) { best_b = d; bk_b = k; }
        }
    }

    dcand[g * NPB + pgrp * 128 + lane]      = best_a;
    kcand[g * NPB + pgrp * 128 + lane]      = bk_a;
    dcand[g * NPB + pgrp * 128 + 64 + lane] = best_b;
    kcand[g * NPB + pgrp * 128 + 64 + lane] = bk_b;
    __syncthreads();

    // combine over ascending k-ranges (strict < keeps first occurrence)
    if (tid < NPB) {
        float bd = dcand[tid];
        int bi = kcand[tid];
        #pragma unroll
        for (int gg = 1; gg < 4; ++gg) {
            float d2 = dcand[gg * NPB + tid];
            int   k2 = kcand[gg * NPB + tid];
            if (d2 < bd) { bd = d2; bi = k2; }
        }
        out[ZQ_ELEMS + n0 + tid] = (float)bi;  // indices (as float32)
        kbest[tid] = bi;
    }
    __syncthreads();

    // z_q: wave (pgrp,g) writes channels [16g,16g+16) for its 128 points;
    // gather from GLOBAL cb (L2-hot) — zero LDS bank conflicts (r8-proven)
    const int bia = kbest[pgrp * 128 + lane];
    const int bib = kbest[pgrp * 128 + 64 + lane];
    const float* rowa = cb + (size_t)bia * CDIM;
    const float* rowb = cb + (size_t)bib * CDIM;
    float* opa = out + (size_t)b * CDIM * HW + hw0 + pgrp * 128 + lane;
    float* opb = opa + 64;
    #pragma unroll
    for (int c = 0; c < 16; ++c) {
        const int ch = g * 16 + c;
        opa[(size_t)ch * HW] = rowa[ch];
        opb[(size_t)ch * HW] = rowb[ch];
    }
}

// ---------------- s_load fallback (proven r5 kernel, 137us) ----------------
__global__ __launch_bounds__(256)
void vq_sload(const float* __restrict__ z_e,
              const float* __restrict__ cb,
              const float* __restrict__ cnorm_g,
              float* __restrict__ out)
{
    __shared__ float cnorm[KCODES];
    __shared__ float dcand[4 * 64];
    __shared__ int   kcand[4 * 64];

    if (cnorm_g) {
        #pragma unroll
        for (int k = (int)threadIdx.x; k < KCODES; k += 256)
            cnorm[k] = cnorm_g[k];
    } else {
        for (int k = (int)threadIdx.x; k < KCODES; k += 256)
            cnorm[k] = cnorm_row(cb + (size_t)k * CDIM);
    }

    const int lane = (int)threadIdx.x & 63;
    const int g = __builtin_amdgcn_readfirstlane((int)threadIdx.x >> 6);
    const int n0 = (int)blockIdx.x * 64;
    const int b = n0 / HW;
    const int hw0 = n0 % HW;
    const float* zp = z_e + (size_t)b * CDIM * HW + hw0 + lane;

    float zz[CDIM];
    #pragma unroll
    for (int m = 0; m < CDIM; ++m)
        zz[m] = zp[(size_t)m * HW];

    float sz = znorm_pairwise(zz);

    __syncthreads();

    float best = 3.4e38f;
    int bk = 0;
    const int k0 = g * 128;

    for (int i = 0; i < 128; ++i) {
        const int k = k0 + i;
        const float* ck = cb + (size_t)k * CDIM;

        float v[16];
        #pragma unroll
        for (int l = 0; l < 16; ++l)
            v[l] = fmaf(zz[l], ck[l],
                     fmaf(zz[16 + l], ck[16 + l],
                       fmaf(zz[32 + l], ck[32 + l],
                         fmaf(zz[48 + l], ck[48 + l], 0.f))));

        float e[8];
        #pragma unroll
        for (int l = 0; l < 8; ++l) e[l] = v[l] + v[8 + l];
        float f[4];
        #pragma unroll
        for (int l = 0; l < 4; ++l) f[l] = e[l] + e[4 + l];
        float g0 = f[0] + f[2];
        float g1 = f[1] + f[3];
        float dot = g0 + g1;

        float A = sz + cnorm[k];
        float d = fmaf(dot, -2.f, A);

        if (d < best) { best = d; bk = k; }
    }

    dcand[g * 64 + lane] = best;
    kcand[g * 64 + lane] = bk;
    __syncthreads();

    float bd = dcand[lane];
    int bi = kcand[lane];
    #pragma unroll
    for (int gg = 1; gg < 4; ++gg) {
        float d2 = dcand[gg * 64 + lane];
        int   k2 = kcand[gg * 64 + lane];
        if (d2 < bd) { bd = d2; bi = k2; }
    }

    if (g == 0) out[ZQ_ELEMS + n0 + lane] = (float)bi;

    const float* row = cb + (size_t)bi * CDIM;
    float* op = out + (size_t)b * CDIM * HW + hw0 + lane;
    #pragma unroll
    for (int c = 0; c < 16; ++c) {
        const int ch = g * 16 + c;
        op[(size_t)ch * HW] = row[ch];
    }
}

extern "C" void kernel_launch(void* const* d_in, const int* in_sizes, int n_in,
                              void* d_out, int out_size, void* d_ws, size_t ws_size,
                              hipStream_t stream) {
    const float* z_e = (const float*)d_in[0];
    const float* cb  = (const float*)d_in[1];
    float* out = (float*)d_out;

    float* cnorm_ws = nullptr;
    if (ws_size >= KCODES * sizeof(float)) {
        cnorm_ws = (float*)d_ws;
        cnorm_kernel<<<dim3(2), dim3(256), 0, stream>>>(cb, cnorm_ws);
    }

    // opt in to >64KB dynamic LDS (gfx950: up to 160KB/workgroup);
    // host-side metadata call, not a stream op (graph-capture safe)
    static int lds_ok = -1;
    if (lds_ok < 0) {
        lds_ok = (hipFuncSetAttribute((const void*)vq_lds,
                                      hipFuncAttributeMaxDynamicSharedMemorySize,
                                      LDS_BYTES) == hipSuccess) ? 1 : 0;
    }

    if (lds_ok == 1) {
        vq_lds<<<dim3(131072 / NPB), dim3(512), LDS_BYTES, stream>>>(
            z_e, cb, cnorm_ws, out);
    } else {
        vq_sload<<<dim3(2048), dim3(256), 0, stream>>>(z_e, cb, cnorm_ws, out);
    }
}